// Round 17
// baseline (61.941 us; speedup 1.0000x reference)
//
#include <hip/hip_runtime.h>

#define CH 512          // targets per LDS chunk
#define TPCH 16         // MFMA tiles per chunk (CH/32)
#define QPB 128         // queries per block (4 waves x 32 cols)
#define YSL 8           // target slices (grid.y)
#define RB 64           // reduction blocks

typedef __bf16 bf16x8 __attribute__((ext_vector_type(8)));
typedef float f32x16 __attribute__((ext_vector_type(16)));

__device__ __forceinline__ unsigned bfb(float x) {
    __bf16 h = (__bf16)x;
    return (unsigned)__builtin_bit_cast(unsigned short, h);
}
__device__ __forceinline__ float bff(unsigned b) {
    return (float)__builtin_bit_cast(__bf16, (unsigned short)b);
}

// async 16B global->LDS copy: LDS dest is wave-uniform base + lane*16 (HW),
// global src is per-lane. Fragments are stored in exactly this order.
__device__ __forceinline__ void gload_lds16(const void* g, void* l) {
    __builtin_amdgcn_global_load_lds(
        (const __attribute__((address_space(1))) unsigned int*)g,
        (__attribute__((address_space(3))) unsigned int*)l, 16, 0, 0);
}

// Fragment build for one target point (same math as before):
// score = (d2 - |q|^2)/4 + 320, window [304,384) in binade [256,512).
// h0 = [xh,xl | xh,xl | yh,yl | yh,yl], h1 = [zh,zl | zh,zl | uh,ul | ull,320]
// Sentinel (p >= nt): coords 0, u=130 -> score 450 (in-window, never wins).
__device__ __forceinline__ void make_frag(float4 p, bool valid, uint4& h0, uint4& h1) {
    float x, y, z, u;
    if (valid) {
        x = p.x; y = p.y; z = p.z;
        u = 0.25f * fmaf(p.x, p.x, fmaf(p.y, p.y, p.z * p.z));
    } else {
        x = 0.f; y = 0.f; z = 0.f; u = 130.f;
    }
    unsigned xh = bfb(x); unsigned xl = bfb(x - bff(xh));
    unsigned yh = bfb(y); unsigned yl = bfb(y - bff(yh));
    unsigned zh = bfb(z); unsigned zl = bfb(z - bff(zh));
    unsigned uh = bfb(u); float u1 = u - bff(uh);
    unsigned ul = bfb(u1); unsigned ull = bfb(u1 - bff(ul));
    h0.x = xh | (xl << 16); h0.y = h0.x;
    h0.z = yh | (yl << 16); h0.w = h0.z;
    h1.x = zh | (zl << 16); h1.y = h1.x;
    h1.z = uh | (ul << 16);
    h1.w = ull | (0x43A0u << 16);      // [ull, bf16(320)]
}

// Precompute A-fragments ONCE per target set, in LDS-load order:
// point p -> frag[(p>>5)*64 + (p&31)] = h0, frag[(p>>5)*64 + 32 + (p&31)] = h1.
// (Previously every one of the 157 query-blocks redid this conversion per chunk.)
__global__ __launch_bounds__(256) void prep(
    const float4* __restrict__ adv, int N,
    const float4* __restrict__ ori, int M,
    uint4* __restrict__ frag0,      // targets for dir 0 (= ori), padded
    uint4* __restrict__ frag1,      // targets for dir 1 (= adv), padded
    int padded)
{
    int p = blockIdx.x * 256 + threadIdx.x;
    if (p >= padded) return;
    int base = (p >> 5) * 64 + (p & 31);
    uint4 h0, h1;
    bool v0 = p < M;
    make_frag(v0 ? ori[p] : make_float4(0.f,0.f,0.f,0.f), v0, h0, h1);
    frag0[base] = h0; frag0[base + 32] = h1;
    bool v1 = p < N;
    make_frag(v1 ? adv[p] : make_float4(0.f,0.f,0.f,0.f), v1, h0, h1);
    frag1[base] = h0; frag1[base + 32] = h1;
}

// MFMA NN scan: rows = targets, cols = queries. Staging is a pure async copy
// (global_load_lds, double-buffered; one barrier per chunk, loads for chunk c+1
// in flight under chunk c's compute). Per-tile reduce: untagged min3 tree over
// raw f32 bits (single positive binade -> u32 cmp == f32 cmp), fold
// (m<<9)|tile7 into two independent chains. After the scan each lane rechecks
// its winning tile's 16 rows with EXACT fp32 d2 (ascending j tie-break), merges
// lane halves via 64-bit shfl_xor, and plain-stores (d2bits<<32)|j into the
// per-(dir,slice) slot row.
__global__ __launch_bounds__(256, 8) void mfma_nn(
    const float4* __restrict__ adv, int N,
    const float4* __restrict__ ori, int M,
    const uint4* __restrict__ frag0,
    const uint4* __restrict__ frag1,
    unsigned long long* __restrict__ slots, int S,   // [2][YSL][S]
    int chunks)
{
    const int dir = blockIdx.z;
    const float4* __restrict__ q = dir ? ori : adv;
    const float4* __restrict__ t = dir ? adv : ori;
    const int nq = dir ? M : N;
    const int nt = dir ? N : M;
    const uint4* __restrict__ frag = dir ? frag1 : frag0;
    unsigned long long* __restrict__ outrow =
        slots + (size_t)(dir * YSL + blockIdx.y) * (size_t)S;

    const int tid = threadIdx.x;
    const int wave = tid >> 6;
    const int lane = tid & 63;
    const int col = lane & 31;
    const int h = lane >> 5;

    const int qi = blockIdx.x * QPB + wave * 32 + col;
    const bool qv = qi < nq;
    float4 qp = qv ? q[qi] : make_float4(0.f, 0.f, 0.f, 0.f);

    // B fragment (queries), c = -q/2 split hi/lo
    float cx = -0.5f * qp.x, cy = -0.5f * qp.y, cz = -0.5f * qp.z;
    unsigned cxh = bfb(cx); unsigned cxl = bfb(cx - bff(cxh));
    unsigned cyh = bfb(cy); unsigned cyl = bfb(cy - bff(cyh));
    unsigned czh = bfb(cz); unsigned czl = bfb(cz - bff(czh));
    uint4 braw;
    if (h == 0) {
        braw.x = cxh | (cxh << 16); braw.y = cxl | (cxl << 16);
        braw.z = cyh | (cyh << 16); braw.w = cyl | (cyl << 16);
    } else {
        braw.x = czh | (czh << 16); braw.y = czl | (czl << 16);
        braw.z = 0x3F803F80u;       braw.w = 0x3F803F80u;   // bf16 1.0 pairs
    }
    const bf16x8 bfrag = __builtin_bit_cast(bf16x8, braw);

    __shared__ uint4 a_lds[2][TPCH * 64];    // 2 x 16 KB
    const f32x16 zero = {};

    const int slicebase = blockIdx.y * chunks * CH;
    const int tbase0 = slicebase >> 5;       // first tile of this slice

    // issue chunk 0 into buf 0: 1024 uint4 per chunk, 4 issues/thread,
    // lds dest uniform per (k, wave); global src per-lane in matching order
    #pragma unroll
    for (int k = 0; k < 4; ++k) {
        int eb = k * 256 + wave * 64;
        gload_lds16(frag + (size_t)tbase0 * 64 + eb + lane, &a_lds[0][eb]);
    }

    unsigned cm0 = 0xFFFFFFFFu;     // (mant23 << 9) | tile7  -- even tiles
    unsigned cm1 = 0xFFFFFFFFu;     //                         -- odd tiles
    int cur = 0;

    for (int c = 0; c < chunks; ++c) {
        __syncthreads();   // drains loads into buf[cur]; all waves done reading buf[cur^1]

        if (c + 1 < chunks) {       // issue next chunk into the other buffer
            int tb = tbase0 + (c + 1) * TPCH;
            #pragma unroll
            for (int k = 0; k < 4; ++k) {
                int eb = k * 256 + wave * 64;
                gload_lds16(frag + (size_t)tb * 64 + eb + lane, &a_lds[cur ^ 1][eb]);
            }
        }

        const unsigned tl0 = (unsigned)(c << 4);
        #pragma unroll
        for (int tt = 0; tt < TPCH; ++tt) {
            bf16x8 a = __builtin_bit_cast(bf16x8, a_lds[cur][tt * 64 + lane]);
            f32x16 acc = __builtin_amdgcn_mfma_f32_32x32x16_bf16(a, bfrag, zero, 0, 0, 0);

            unsigned u0 = min(min(__float_as_uint(acc[0]),  __float_as_uint(acc[1])),  __float_as_uint(acc[2]));
            unsigned u1 = min(min(__float_as_uint(acc[3]),  __float_as_uint(acc[4])),  __float_as_uint(acc[5]));
            unsigned u2 = min(min(__float_as_uint(acc[6]),  __float_as_uint(acc[7])),  __float_as_uint(acc[8]));
            unsigned u3 = min(min(__float_as_uint(acc[9]),  __float_as_uint(acc[10])), __float_as_uint(acc[11]));
            unsigned u4 = min(min(__float_as_uint(acc[12]), __float_as_uint(acc[13])), __float_as_uint(acc[14]));
            unsigned u5 = min(min(u0, u1), u2);
            unsigned u6 = min(min(u3, u4), __float_as_uint(acc[15]));
            unsigned m  = min(u5, u6);

            unsigned key = (m << 9) | (tl0 + (unsigned)tt);
            if (tt & 1) cm1 = min(cm1, key);
            else        cm0 = min(cm0, key);
        }
        cur ^= 1;
    }

    const unsigned cm = min(cm0, cm1);

    // exact recheck: 16 candidate rows of the winning tile (my lane-half)
    const int jb = slicebase + (int)(cm & 0x7Fu) * 32 + 4 * h;
    unsigned long long run = 0xFFFFFFFFFFFFFFFFull;
    #pragma unroll
    for (int e = 0; e < 16; ++e) {
        int r = (e & 3) + ((e >> 2) << 3);      // ascending j within the half
        int j = jb + r;
        if (j < nt) {
            float4 b = t[j];
            float dx = qp.x - b.x, dy = qp.y - b.y, dz = qp.z - b.z;
            float d2 = fmaf(dx, dx, fmaf(dy, dy, dz * dz));
            unsigned long long cand =
                ((unsigned long long)__float_as_uint(d2) << 32) | (unsigned)j;
            run = cand < run ? cand : run;
        }
    }

    // merge lane halves (same query col, disjoint row halves), plain store
    unsigned long long other = __shfl_xor(run, 32);
    run = run < other ? run : other;
    if (h == 0 && qv) outrow[qi] = run;
}

__device__ inline float block_reduce_sum(float v, float* lds) {
    #pragma unroll
    for (int off = 32; off > 0; off >>= 1) v += __shfl_down(v, off, 64);
    int wave = threadIdx.x >> 6;
    int lane = threadIdx.x & 63;
    __syncthreads();
    if (lane == 0) lds[wave] = v;
    __syncthreads();
    float r = 0.f;
    if (threadIdx.x == 0) {
        #pragma unroll
        for (int w = 0; w < 4; ++w) r += lds[w];
    }
    return r;  // valid on thread 0 only
}

// Stage 1: RB blocks, fixed partition -> deterministic partial sums.
__global__ __launch_bounds__(256) void partial_finalize(
    const unsigned long long* __restrict__ slots, int S,   // [2][YSL][S]
    int n, int m,
    const float4* __restrict__ adv, const float4* __restrict__ ori,
    float* __restrict__ partials)                           // RB*4 floats
{
    __shared__ float lds[4];
    float s_min0 = 0.f, s_i1 = 0.f, s_min1 = 0.f, s_i2 = 0.f;
    const int stride = RB * 256;
    const int t0 = blockIdx.x * 256 + threadIdx.x;
    const unsigned long long* __restrict__ s0 = slots;
    const unsigned long long* __restrict__ s1 = slots + (size_t)YSL * S;

    for (int i = t0; i < n; i += stride) {
        unsigned long long k = s0[i];
        #pragma unroll
        for (int y = 1; y < YSL; ++y) k = min(k, s0[(size_t)y * S + i]);
        int j = (int)(unsigned int)(k & 0xFFFFFFFFu);
        s_min0 += __uint_as_float((unsigned int)(k >> 32));
        float dw = adv[i].w - ori[j].w;
        s_i1 += dw * dw;
    }
    for (int jj = t0; jj < m; jj += stride) {
        unsigned long long k = s1[jj];
        #pragma unroll
        for (int y = 1; y < YSL; ++y) k = min(k, s1[(size_t)y * S + jj]);
        int i = (int)(unsigned int)(k & 0xFFFFFFFFu);
        s_min1 += __uint_as_float((unsigned int)(k >> 32));
        float dw = ori[jj].w - adv[i].w;
        s_i2 += dw * dw;
    }

    float r0 = block_reduce_sum(s_min0, lds);
    float r1 = block_reduce_sum(s_i1, lds);
    float r2 = block_reduce_sum(s_min1, lds);
    float r3 = block_reduce_sum(s_i2, lds);

    if (threadIdx.x == 0) {
        partials[blockIdx.x * 4 + 0] = r0;
        partials[blockIdx.x * 4 + 1] = r1;
        partials[blockIdx.x * 4 + 2] = r2;
        partials[blockIdx.x * 4 + 3] = r3;
    }
}

__global__ __launch_bounds__(256) void combine(
    const float* __restrict__ partials, int n, int m, float* __restrict__ out)
{
    __shared__ float lds[4];
    float v0 = 0.f, v1 = 0.f, v2 = 0.f, v3 = 0.f;
    if (threadIdx.x < RB) {
        v0 = partials[threadIdx.x * 4 + 0];
        v1 = partials[threadIdx.x * 4 + 1];
        v2 = partials[threadIdx.x * 4 + 2];
        v3 = partials[threadIdx.x * 4 + 3];
    }
    float r0 = block_reduce_sum(v0, lds);
    float r1 = block_reduce_sum(v1, lds);
    float r2 = block_reduce_sum(v2, lds);
    float r3 = block_reduce_sum(v3, lds);
    if (threadIdx.x == 0) {
        float chamfer   = r0 / (float)n + r2 / (float)m;
        float intensity = 0.5f * (r1 / (float)n + r3 / (float)m);
        out[0] = chamfer * 1.0f + intensity * 0.5f;
    }
}

extern "C" void kernel_launch(void* const* d_in, const int* in_sizes, int n_in,
                              void* d_out, int out_size, void* d_ws, size_t ws_size,
                              hipStream_t stream) {
    const float4* adv = (const float4*)d_in[0];
    const float4* ori = (const float4*)d_in[1];
    const int N = in_sizes[0] / 4;
    const int M = in_sizes[1] / 4;
    const int S = max(N, M);

    const int chunks = (S + YSL * CH - 1) / (YSL * CH);          // chunks per slice
    const int padded = YSL * chunks * CH;                        // padded target count

    unsigned long long* slots = (unsigned long long*)d_ws;       // 2*YSL*S u64
    uint4* frag0 = (uint4*)(slots + (size_t)2 * YSL * S);        // padded*2 uint4
    uint4* frag1 = frag0 + (size_t)padded * 2;                   // padded*2 uint4
    float* partials = (float*)(frag1 + (size_t)padded * 2);      // RB*4 floats
    float* out = (float*)d_out;

    prep<<<(padded + 255) / 256, 256, 0, stream>>>(adv, N, ori, M, frag0, frag1, padded);

    dim3 grid((S + QPB - 1) / QPB, YSL, 2);
    mfma_nn<<<grid, 256, 0, stream>>>(adv, N, ori, M, frag0, frag1, slots, S, chunks);

    partial_finalize<<<RB, 256, 0, stream>>>(slots, S, N, M, adv, ori, partials);
    combine<<<1, 256, 0, stream>>>(partials, N, M, out);
}

// Round 18
// 48.316 us; speedup vs baseline: 1.2820x; 1.2820x over previous
//
#include <hip/hip_runtime.h>

#define CH 512          // targets per LDS chunk
#define TPCH 16         // MFMA tiles per chunk (CH/32)
#define QPB 128         // queries per block (4 waves x 32 cols)
#define YSL 8           // target slices (grid.y)
#define RB 64           // reduction blocks

typedef __bf16 bf16x8 __attribute__((ext_vector_type(8)));
typedef float f32x16 __attribute__((ext_vector_type(16)));

__device__ __forceinline__ unsigned bfb(float x) {
    __bf16 h = (__bf16)x;
    return (unsigned)__builtin_bit_cast(unsigned short, h);
}
__device__ __forceinline__ float bff(unsigned b) {
    return (float)__builtin_bit_cast(__bf16, (unsigned short)b);
}

// Build the A-fragment (targets) for one local row of the chunk.
// K-slot map (k: A | B):  score = (d2 - |q|^2)/4 + 320, window [304,384) in [256,512)
//  k0..3 : [xh, xl, xh, xl] | [cxh, cxh, cxl, cxl]   (full (xh+xl)(cxh+cxl))
//  k4..7 : [yh, yl, yh, yl] | [cyh, cyh, cyl, cyl]
//  k8..11: [zh, zl, zh, zl] | [czh, czh, czl, czl]
//  k12..15:[uh, ul, ull,320]| [1, 1, 1, 1]           (u = |t|^2/4, 3-term split)
// Sentinel rows: coords 0, u=130 -> score 450 (in-window, never beats real <384).
__device__ __forceinline__ void stage_one(uint4* a_lds, int local, float4 p, bool valid) {
    float x, y, z, u;
    if (valid) {
        x = p.x; y = p.y; z = p.z;
        u = 0.25f * fmaf(p.x, p.x, fmaf(p.y, p.y, p.z * p.z));
    } else {
        x = 0.f; y = 0.f; z = 0.f; u = 130.f;
    }
    unsigned xh = bfb(x); unsigned xl = bfb(x - bff(xh));
    unsigned yh = bfb(y); unsigned yl = bfb(y - bff(yh));
    unsigned zh = bfb(z); unsigned zl = bfb(z - bff(zh));
    unsigned uh = bfb(u); float u1 = u - bff(uh);
    unsigned ul = bfb(u1); unsigned ull = bfb(u1 - bff(ul));
    uint4 h0, h1;
    h0.x = xh | (xl << 16); h0.y = h0.x;
    h0.z = yh | (yl << 16); h0.w = h0.z;
    h1.x = zh | (zl << 16); h1.y = h1.x;
    h1.z = uh | (ul << 16);
    h1.w = ull | (0x43A0u << 16);      // [ull, bf16(320)]
    int t = local >> 5, r = local & 31;
    a_lds[t * 64 + r]      = h0;       // k-half 0 (lanes 0-31)
    a_lds[t * 64 + 32 + r] = h1;       // k-half 1 (lanes 32-63)
}

// 16-element untagged min3 tree over raw f32 bits + fold into chain.
__device__ __forceinline__ void reduce_tile(const f32x16& acc, unsigned tl, unsigned& cmE, unsigned& cmO, bool odd) {
    unsigned u0 = min(min(__float_as_uint(acc[0]),  __float_as_uint(acc[1])),  __float_as_uint(acc[2]));
    unsigned u1 = min(min(__float_as_uint(acc[3]),  __float_as_uint(acc[4])),  __float_as_uint(acc[5]));
    unsigned u2 = min(min(__float_as_uint(acc[6]),  __float_as_uint(acc[7])),  __float_as_uint(acc[8]));
    unsigned u3 = min(min(__float_as_uint(acc[9]),  __float_as_uint(acc[10])), __float_as_uint(acc[11]));
    unsigned u4 = min(min(__float_as_uint(acc[12]), __float_as_uint(acc[13])), __float_as_uint(acc[14]));
    unsigned u5 = min(min(u0, u1), u2);
    unsigned u6 = min(min(u3, u4), __float_as_uint(acc[15]));
    unsigned m  = min(u5, u6);
    unsigned key = (m << 9) | tl;
    if (odd) cmO = min(cmO, key);
    else     cmE = min(cmE, key);
}

// MFMA NN scan (R12 structure + software-pipelined reduce):
// rows = targets, cols = queries; per-tile reduce of tile t runs while tile
// t+1's MFMA is in flight (separate pipes) -- 2-stage rotation with NAMED acc
// registers (accA/accB) so all indexing is compile-time (no scratch).
// Key math unchanged: untagged tree, (m<<9)|tile7 fold (single positive binade
// -> u32 cmp == f32 cmp, all 23 mantissa bits kept, lower tile wins ties);
// exact fp32 recheck of the winning tile's 16 rows afterward; lane halves
// merged via 64-bit shfl_xor; plain store into per-(dir,slice) slot row.
__global__ __launch_bounds__(256, 8) void mfma_nn(
    const float4* __restrict__ adv, int N,
    const float4* __restrict__ ori, int M,
    unsigned long long* __restrict__ slots, int S,   // [2][YSL][S]
    int chunks)
{
    const int dir = blockIdx.z;
    const float4* __restrict__ q = dir ? ori : adv;
    const float4* __restrict__ t = dir ? adv : ori;
    const int nq = dir ? M : N;
    const int nt = dir ? N : M;
    unsigned long long* __restrict__ outrow =
        slots + (size_t)(dir * YSL + blockIdx.y) * (size_t)S;

    const int tid = threadIdx.x;
    const int wave = tid >> 6;
    const int lane = tid & 63;
    const int col = lane & 31;
    const int h = lane >> 5;

    const int qi = blockIdx.x * QPB + wave * 32 + col;
    const bool qv = qi < nq;
    float4 qp = qv ? q[qi] : make_float4(0.f, 0.f, 0.f, 0.f);

    // B fragment (queries), c = -q/2 split hi/lo
    float cx = -0.5f * qp.x, cy = -0.5f * qp.y, cz = -0.5f * qp.z;
    unsigned cxh = bfb(cx); unsigned cxl = bfb(cx - bff(cxh));
    unsigned cyh = bfb(cy); unsigned cyl = bfb(cy - bff(cyh));
    unsigned czh = bfb(cz); unsigned czl = bfb(cz - bff(czh));
    uint4 braw;
    if (h == 0) {
        braw.x = cxh | (cxh << 16); braw.y = cxl | (cxl << 16);
        braw.z = cyh | (cyh << 16); braw.w = cyl | (cyl << 16);
    } else {
        braw.x = czh | (czh << 16); braw.y = czl | (czl << 16);
        braw.z = 0x3F803F80u;       braw.w = 0x3F803F80u;   // bf16 1.0 pairs
    }
    const bf16x8 bfrag = __builtin_bit_cast(bf16x8, braw);

    __shared__ uint4 a_lds[TPCH * 64];
    const f32x16 zero = {};

    const int slicebase = blockIdx.y * chunks * CH;
    unsigned cm0 = 0xFFFFFFFFu;     // (mant23 << 9) | tile7  -- even tiles
    unsigned cm1 = 0xFFFFFFFFu;     //                         -- odd tiles
    int base = slicebase;

    for (int c = 0; c < chunks; ++c) {
        if (c) __syncthreads();                 // prior tile reads done
        {
            int j0 = base + tid, j1 = j0 + 256;
            if (base + CH <= nt) {              // block-uniform fast path
                stage_one(a_lds, tid,       t[j0], true);
                stage_one(a_lds, tid + 256, t[j1], true);
            } else {
                bool v0 = j0 < nt, v1 = j1 < nt;
                float4 p0 = v0 ? t[j0] : make_float4(0.f, 0.f, 0.f, 0.f);
                float4 p1 = v1 ? t[j1] : make_float4(0.f, 0.f, 0.f, 0.f);
                stage_one(a_lds, tid,       p0, v0);
                stage_one(a_lds, tid + 256, p1, v1);
            }
        }
        __syncthreads();

        const unsigned tl0 = (unsigned)(c << 4);

        // 2-stage pipeline: MFMA(tt) issues, then reduce(tt-1) runs under it.
        f32x16 accA, accB;
        accA = __builtin_amdgcn_mfma_f32_32x32x16_bf16(
            __builtin_bit_cast(bf16x8, a_lds[0 * 64 + lane]), bfrag, zero, 0, 0, 0);
        #pragma unroll
        for (int tt = 1; tt < TPCH; tt += 2) {
            accB = __builtin_amdgcn_mfma_f32_32x32x16_bf16(
                __builtin_bit_cast(bf16x8, a_lds[tt * 64 + lane]), bfrag, zero, 0, 0, 0);
            reduce_tile(accA, tl0 + (unsigned)(tt - 1), cm0, cm1, false);
            accA = __builtin_amdgcn_mfma_f32_32x32x16_bf16(
                __builtin_bit_cast(bf16x8, a_lds[(tt + 1 < TPCH ? tt + 1 : 0) * 64 + lane]),
                bfrag, zero, 0, 0, 0);
            reduce_tile(accB, tl0 + (unsigned)tt, cm0, cm1, true);
        }
        // TPCH even: the loop's last accA (tt+1 == TPCH wrapped to 0) is a
        // redundant recompute of tile 0 -- reduce it is WRONG; instead the loop
        // covered tiles 0..15 already (accA reduced at tt-1 for even tiles,
        // accB at tt for odd). The wrapped MFMA result is simply dropped.
        (void)accA;
        base += CH;
    }

    const unsigned cm = min(cm0, cm1);

    // exact recheck: 16 candidate rows of the winning tile (my lane-half)
    const int jb = slicebase + (int)(cm & 0x7Fu) * 32 + 4 * h;
    unsigned long long run = 0xFFFFFFFFFFFFFFFFull;
    #pragma unroll
    for (int e = 0; e < 16; ++e) {
        int r = (e & 3) + ((e >> 2) << 3);      // ascending j within the half
        int j = jb + r;
        if (j < nt) {
            float4 b = t[j];
            float dx = qp.x - b.x, dy = qp.y - b.y, dz = qp.z - b.z;
            float d2 = fmaf(dx, dx, fmaf(dy, dy, dz * dz));
            unsigned long long cand =
                ((unsigned long long)__float_as_uint(d2) << 32) | (unsigned)j;
            run = cand < run ? cand : run;
        }
    }

    // merge lane halves (same query col, disjoint row halves), plain store
    unsigned long long other = __shfl_xor(run, 32);
    run = run < other ? run : other;
    if (h == 0 && qv) outrow[qi] = run;
}

__device__ inline float block_reduce_sum(float v, float* lds) {
    #pragma unroll
    for (int off = 32; off > 0; off >>= 1) v += __shfl_down(v, off, 64);
    int wave = threadIdx.x >> 6;
    int lane = threadIdx.x & 63;
    __syncthreads();
    if (lane == 0) lds[wave] = v;
    __syncthreads();
    float r = 0.f;
    if (threadIdx.x == 0) {
        #pragma unroll
        for (int w = 0; w < 4; ++w) r += lds[w];
    }
    return r;  // valid on thread 0 only
}

// Stage 1: RB blocks, fixed partition -> deterministic partial sums.
// Per query: u64-min over the YSL slice slots (d2 exact; lower j wins ties ->
// numpy first-occurrence since slice j-ranges ascend).
__global__ __launch_bounds__(256) void partial_finalize(
    const unsigned long long* __restrict__ slots, int S,   // [2][YSL][S]
    int n, int m,
    const float4* __restrict__ adv, const float4* __restrict__ ori,
    float* __restrict__ partials)                           // RB*4 floats
{
    __shared__ float lds[4];
    float s_min0 = 0.f, s_i1 = 0.f, s_min1 = 0.f, s_i2 = 0.f;
    const int stride = RB * 256;
    const int t0 = blockIdx.x * 256 + threadIdx.x;
    const unsigned long long* __restrict__ s0 = slots;
    const unsigned long long* __restrict__ s1 = slots + (size_t)YSL * S;

    for (int i = t0; i < n; i += stride) {
        unsigned long long k = s0[i];
        #pragma unroll
        for (int y = 1; y < YSL; ++y) k = min(k, s0[(size_t)y * S + i]);
        int j = (int)(unsigned int)(k & 0xFFFFFFFFu);
        s_min0 += __uint_as_float((unsigned int)(k >> 32));
        float dw = adv[i].w - ori[j].w;
        s_i1 += dw * dw;
    }
    for (int jj = t0; jj < m; jj += stride) {
        unsigned long long k = s1[jj];
        #pragma unroll
        for (int y = 1; y < YSL; ++y) k = min(k, s1[(size_t)y * S + jj]);
        int i = (int)(unsigned int)(k & 0xFFFFFFFFu);
        s_min1 += __uint_as_float((unsigned int)(k >> 32));
        float dw = ori[jj].w - adv[i].w;
        s_i2 += dw * dw;
    }

    float r0 = block_reduce_sum(s_min0, lds);
    float r1 = block_reduce_sum(s_i1, lds);
    float r2 = block_reduce_sum(s_min1, lds);
    float r3 = block_reduce_sum(s_i2, lds);

    if (threadIdx.x == 0) {
        partials[blockIdx.x * 4 + 0] = r0;
        partials[blockIdx.x * 4 + 1] = r1;
        partials[blockIdx.x * 4 + 2] = r2;
        partials[blockIdx.x * 4 + 3] = r3;
    }
}

__global__ __launch_bounds__(256) void combine(
    const float* __restrict__ partials, int n, int m, float* __restrict__ out)
{
    __shared__ float lds[4];
    float v0 = 0.f, v1 = 0.f, v2 = 0.f, v3 = 0.f;
    if (threadIdx.x < RB) {
        v0 = partials[threadIdx.x * 4 + 0];
        v1 = partials[threadIdx.x * 4 + 1];
        v2 = partials[threadIdx.x * 4 + 2];
        v3 = partials[threadIdx.x * 4 + 3];
    }
    float r0 = block_reduce_sum(v0, lds);
    float r1 = block_reduce_sum(v1, lds);
    float r2 = block_reduce_sum(v2, lds);
    float r3 = block_reduce_sum(v3, lds);
    if (threadIdx.x == 0) {
        float chamfer   = r0 / (float)n + r2 / (float)m;
        float intensity = 0.5f * (r1 / (float)n + r3 / (float)m);
        out[0] = chamfer * 1.0f + intensity * 0.5f;
    }
}

extern "C" void kernel_launch(void* const* d_in, const int* in_sizes, int n_in,
                              void* d_out, int out_size, void* d_ws, size_t ws_size,
                              hipStream_t stream) {
    const float4* adv = (const float4*)d_in[0];
    const float4* ori = (const float4*)d_in[1];
    const int N = in_sizes[0] / 4;
    const int M = in_sizes[1] / 4;
    const int S = max(N, M);

    unsigned long long* slots = (unsigned long long*)d_ws;       // 2*YSL*S entries
    float* partials = (float*)(slots + (size_t)2 * YSL * S);     // RB*4 floats
    float* out = (float*)d_out;

    const int chunks = (S + YSL * CH - 1) / (YSL * CH);          // chunks per slice
    dim3 grid((S + QPB - 1) / QPB, YSL, 2);
    mfma_nn<<<grid, 256, 0, stream>>>(adv, N, ori, M, slots, S, chunks);

    partial_finalize<<<RB, 256, 0, stream>>>(slots, S, N, M, adv, ori, partials);
    combine<<<1, 256, 0, stream>>>(partials, N, M, out);
}